// Round 6
// baseline (1842.006 us; speedup 1.0000x reference)
//
#include <hip/hip_runtime.h>

#define BT   (512*256)
// hbuf layout (shorts): zeros @0..127, b0 h @128..255, b1 h @288..415
#define HB0  128
#define HB1  288
#define HLEN 448
#define NG   2        // independent wave-groups per block (decoupled barriers)

using short8  = __attribute__((ext_vector_type(8))) short;
using floatx4 = __attribute__((ext_vector_type(4))) float;

__device__ inline unsigned short f2bf(float f){
  unsigned int u = __float_as_uint(f);
  u += 0x7FFFu + ((u >> 16) & 1u);          // RNE
  return (unsigned short)(u >> 16);
}
__device__ inline float bf2f(unsigned short u){
  return __uint_as_float(((unsigned int)u) << 16);
}
__device__ inline float rcpf(float x){ return __builtin_amdgcn_rcpf(x); }

// 128 blocks x 512 threads = 2 groups x 4 waves. Group g handles batches
// 2*(2*bb+g), +1 with the round-5 M=2 structure, but groups sync on their OWN
// LDS counter (not __syncthreads) so the two groups drift out of phase: each
// SIMD holds one wave of each group, and one group's MFMA bursts fill the
// other group's serial phases (read latency, nonlinearity, sync wait).
// No global memory ops inside the loop -> syncs never wait on vmcnt.
__global__ __launch_bounds__(512,2) void k_seq(
    const float* __restrict__ in,
    const float* __restrict__ Wih,  const float* __restrict__ Whh,
    const float* __restrict__ bih,  const float* __restrict__ bhh,
    const float* __restrict__ fc1w, const float* __restrict__ fc1b,
    const float* __restrict__ fc2w, const float* __restrict__ fc2b,
    const float* __restrict__ i1w,  const float* __restrict__ i1b,
    const float* __restrict__ i3w,  const float* __restrict__ i3b,
    const float* __restrict__ scw,  const float* __restrict__ zonew,
    float* __restrict__ out)
{
  __shared__ __align__(16) unsigned short hbuf[NG][2][HLEN];
  __shared__ __align__(16) unsigned short xgu [NG][8192];  // [k][b][512] bf16 gates
  __shared__ __align__(8)  unsigned short toutl[NG][512];  // bf16 TOut history
  __shared__ __align__(8)  unsigned short extl [NG][512];  // bf16 Ext results
  __shared__ __align__(8)  unsigned short exl  [NG][2048]; // bf16 Ext_X cols [b*256+t][4]
  __shared__ float t0l  [NG][512];    // T0 (f32)
  __shared__ float hvitl[NG][512];    // HVAC + int_all (f32)
  __shared__ float obuf [NG][256];
  __shared__ float E_l  [NG][2];
  __shared__ unsigned int ctr[NG*16];

  const int tid = threadIdx.x;
  const int g   = tid >> 8;             // group 0/1
  const int t   = tid & 255;            // group-local tid
  const int wv  = t >> 6;               // group-local wave 0..3
  const int ln  = t & 63;
  const int l15 = ln & 15;
  const int quad= ln >> 4;
  const int vbb = blockIdx.x*NG + g;    // virtual block 0..255

  // ---- init: stage per-group tables, zero hbuf ----
  for(int p=t; p<512; p+=256){
    int b=p>>8, tt=p&255;
    const float* row = in + (2*vbb+b)*1792 + tt*7;
    t0l[g][p] = row[0];
    exl[g][p*4+0]=f2bf(row[1]); exl[g][p*4+1]=f2bf(row[2]);
    exl[g][p*4+2]=f2bf(row[3]); exl[g][p*4+3]=f2bf(row[4]);
  }
  for(int p=t; p<2*HLEN; p+=256) ((unsigned short*)hbuf[g])[p]=0;
  hbuf[g][0][HB0 + (t>>7)*(HB1-HB0) + (t&127)] = 0x3F80;   // h = 1.0
  if(t<16) toutl[g][(t>>3)*256+(t&7)] = f2bf(in[(2*vbb+(t>>3))*1792+(t&7)*7]);
  if(t<2)  E_l[g][t] = in[(2*vbb+t)*1792 + 56];            // E = T0[:,8]
  if(t==0) ctr[g*16]=0;
  // int-module weight scratch in xgu region (overwritten later, after a sync)
  float* lw4 = (float*)&xgu[g][0];      // 128 x {w0,w1,w2,b}
  float* l3  = lw4 + 512;
  if(t<128){
    lw4[t*4+0]=i1w[t*3+0]; lw4[t*4+1]=i1w[t*3+1];
    lw4[t*4+2]=i1w[t*3+2]; lw4[t*4+3]=i1b[t];
    l3[t]=i3w[t];
  }
  __syncthreads();                      // one full-block barrier, init only

  // ---- fused int module (writes Int/HVAC/TOut[0:8]/Ext[0:8] to global) ----
  {
    const float b30=i3b[0], sc0=scw[0];
    #pragma unroll
    for(int b=0;b<2;b++){
      const float* row = in + (2*vbb+b)*1792 + t*7;
      float x0=row[3],x1=row[4],x2=row[5], acc=0.f;
      #pragma unroll 8
      for(int j=0;j<128;j++){
        float r=fmaxf(lw4[j*4]*x0+lw4[j*4+1]*x1+lw4[j*4+2]*x2+lw4[j*4+3],0.f);
        acc += r*l3[j];
      }
      float v = rcpf(1.f+__expf(-(acc+b30)))*sc0;
      float itv = (t<8)?0.f:v;
      int gb = 2*vbb+b;
      hvitl[g][b*256+t] = row[6] + itv;
      out[3*BT+gb*256+t]=itv;            // Int_list
      out[BT+gb*256+t]=row[6];           // HVAC_list
      if(t<8){ out[gb*256+t]=row[0]; out[2*BT+gb*256+t]=0.f; }
    }
  }

  // ---- weight fragments into VGPRs ----
  short8 wfr[4][2][4];   // [gate][hh][Kchunk], rows n = 128g + 32wv + 16hh + l15
  short8 xfr[4][2];
  short8 ffr[2][4];
  float  bsum[4][2];
  #pragma unroll
  for(int gg=0;gg<4;gg++){
    #pragma unroll
    for(int hh=0;hh<2;hh++){
      int n = 128*gg + 32*wv + 16*hh + l15;
      bsum[gg][hh] = bih[n]+bhh[n];
      #pragma unroll
      for(int Q=0;Q<4;Q++){
        short8 f;
        #pragma unroll
        for(int j=0;j<8;j++) f[j]=(short)f2bf(Whh[n*128 + Q*32 + quad*8 + j]);
        wfr[gg][hh][Q]=f;
      }
      short8 f;
      #pragma unroll
      for(int j=0;j<8;j++){ int kk=quad*8+j; f[j]=(short)f2bf(kk<5?Wih[n*5+kk]:0.f); }
      xfr[gg][hh]=f;
    }
  }
  #pragma unroll
  for(int hh=0;hh<2;hh++){
    int n = 32*wv + 16*hh + l15;
    #pragma unroll
    for(int Q=0;Q<4;Q++){
      short8 f;
      #pragma unroll
      for(int j=0;j<8;j++) f[j]=(short)f2bf(fc1w[n*128 + Q*32 + quad*8 + j]);
      ffr[hh][Q]=f;
    }
  }

  // ---- per-lane persistent scalars ----
  const int  u     = 32*wv + 16*(quad>>1) + l15;
  const int  bm    = quad & 1;
  const bool hi2   = quad >= 2;
  const int  aoff  = ((l15&3)==0) ? (HB0 + ((l15>>2)&1)*(HB1-HB0) + quad*8)
                                  : (quad*8);            // zero region
  const int  xbase = bm*512 + u;
  const int  hwoff = HB0 + bm*(HB1-HB0) + u;
  const float fb    = fc1b[u];
  const float fw0   = fc2w[ln];
  const float fw1   = fc2w[64+ln];
  const float fc2b0 = fc2b[0];
  const float zw    = zonew[0];
  const floatx4 ZV  = {0.f,0.f,0.f,0.f};
  float c0 = 1.f;

  // ---- group-local sync (decoupled between groups; never waits vmcnt) ----
  unsigned int tgt = 0;
  volatile unsigned int* vct = (volatile unsigned int*)&ctr[g*16];
  #define GSYNC() do{ tgt += 4; __threadfence_block();                    \
      if(ln==0) atomicAdd((unsigned int*)&ctr[g*16], 1u);                 \
      while(*vct < tgt){}                                                 \
      __threadfence_block(); }while(0)

  GSYNC();   // int-module scratch reads done in all group waves -> xgu reusable

  #pragma unroll 1
  for(int i=8;i<256;i++){
    // ===== phase A: toutl[i]=E; embed in registers; x-MFMA =====
    if(t<2) toutl[g][t*256+i] = f2bf(E_l[g][t]);
    {
      short8 ea = 0;
      if(quad==0){
        int bE=l15>>3, kk=l15&7, p=i-7+kk;
        float t0v = t0l[g][bE*256+p];
        float tos = (p==i) ? E_l[g][bE] : bf2f(toutl[g][bE*256+p]);
        float tmix;
        if(i<128){
          float ratio=(float)i*0.0078125f;
          tmix = t0v*ratio + tos*(1.f-ratio);
        } else tmix = tos;
        ea[0]=(short)f2bf(tmix);
        ea[1]=(short)exl[g][(bE*256+p)*4+0]; ea[2]=(short)exl[g][(bE*256+p)*4+1];
        ea[3]=(short)exl[g][(bE*256+p)*4+2]; ea[4]=(short)exl[g][(bE*256+p)*4+3];
      }
      #pragma unroll
      for(int gg=0;gg<4;gg++){
        #pragma unroll
        for(int hh=0;hh<2;hh++){
          floatx4 z=__builtin_amdgcn_mfma_f32_16x16x32_bf16(ea, xfr[gg][hh], ZV,0,0,0);
          #pragma unroll
          for(int r=0;r<4;r++){
            int m=4*quad+r;               // m = b*8+k
            xgu[g][(m&7)*1024 + (m>>3)*512 + 128*gg + 32*wv+16*hh+l15]
              = f2bf(z[r]+bsum[gg][hh]);
          }
        }
      }
    }
    GSYNC();

    // ===== 8 inner LSTM steps =====
    #pragma unroll
    for(int k=0;k<8;k++){
      float xv0=bf2f(xgu[g][k*1024+xbase    ]);
      float xv1=bf2f(xgu[g][k*1024+xbase+128]);
      float xv2=bf2f(xgu[g][k*1024+xbase+256]);
      float xv3=bf2f(xgu[g][k*1024+xbase+384]);
      const unsigned short* ab = &hbuf[g][k&1][0] + aoff;
      short8 a0=*(const short8*)(ab);
      short8 a1=*(const short8*)(ab+32);
      short8 a2=*(const short8*)(ab+64);
      short8 a3=*(const short8*)(ab+96);
      floatx4 acc[4][2];
      #pragma unroll
      for(int gg=0;gg<4;gg++){
        #pragma unroll
        for(int hh=0;hh<2;hh++){
          floatx4 z=__builtin_amdgcn_mfma_f32_16x16x32_bf16(a0,wfr[gg][hh][0],ZV,0,0,0);
          z=__builtin_amdgcn_mfma_f32_16x16x32_bf16(a1,wfr[gg][hh][1],z,0,0,0);
          z=__builtin_amdgcn_mfma_f32_16x16x32_bf16(a2,wfr[gg][hh][2],z,0,0,0);
          z=__builtin_amdgcn_mfma_f32_16x16x32_bf16(a3,wfr[gg][hh][3],z,0,0,0);
          acc[gg][hh]=z;
        }
      }
      float gi=(hi2?acc[0][1][0]:acc[0][0][0])+xv0;
      float gf=(hi2?acc[1][1][0]:acc[1][0][0])+xv1;
      float gg2=(hi2?acc[2][1][0]:acc[2][0][0])+xv2;
      float go=(hi2?acc[3][1][0]:acc[3][0][0])+xv3;
      float ef =__expf(-gf);
      float egi=__expf(-gi);
      float egg=__expf(-2.f*gg2);
      float sf = rcpf(1.f+ef);
      float itn=(1.f-egg)*rcpf((1.f+egi)*(1.f+egg));
      c0 = sf*c0 + itn;
      float ego=__expf(-go);
      float ec =__expf(-2.f*c0);
      float hv2=(1.f-ec)*rcpf((1.f+ego)*(1.f+ec));
      hbuf[g][(k+1)&1][hwoff]=f2bf(hv2);
      GSYNC();
    }

    // ===== fc1 (h in buf 0 after k=7) =====
    {
      const unsigned short* ab = &hbuf[g][0][0] + aoff;
      short8 a0=*(const short8*)(ab);
      short8 a1=*(const short8*)(ab+32);
      short8 a2=*(const short8*)(ab+64);
      short8 a3=*(const short8*)(ab+96);
      floatx4 fa[2];
      #pragma unroll
      for(int hh=0;hh<2;hh++){
        floatx4 z=__builtin_amdgcn_mfma_f32_16x16x32_bf16(a0,ffr[hh][0],ZV,0,0,0);
        z=__builtin_amdgcn_mfma_f32_16x16x32_bf16(a1,ffr[hh][1],z,0,0,0);
        z=__builtin_amdgcn_mfma_f32_16x16x32_bf16(a2,ffr[hh][2],z,0,0,0);
        z=__builtin_amdgcn_mfma_f32_16x16x32_bf16(a3,ffr[hh][3],z,0,0,0);
        fa[hh]=z;
      }
      float fv = hi2 ? fa[1][0] : fa[0][0];
      obuf[g][bm*128+u]=fmaxf(fv+fb,0.f);
    }
    GSYNC();

    // ===== fc2 + E update (group waves 0,1 = batch 0,1) =====
    if(wv<2){
      float v = obuf[g][wv*128+ln]*fw0 + obuf[g][wv*128+64+ln]*fw1;
      #pragma unroll
      for(int off=32; off; off>>=1) v += __shfl_xor(v, off, 64);
      if(ln==0){
        float ext   = v + fc2b0;
        float total = ext + hvitl[g][wv*256+i];
        float E = E_l[g][wv];
        if(i<128){
          float ratio=(float)i*0.0078125f;
          E = ratio*t0l[g][wv*256+i] + (1.f-ratio)*E + total*zw;
        } else {
          E = E + total*zw;
        }
        E_l[g][wv]=E;
        extl[g][wv*256+i]=f2bf(ext);
      }
    }
    GSYNC();
  }

  // ===== flush TOut / Ext_list from LDS (group-local; last GSYNC ordered) =====
  for(int p=t; p<496; p+=256){
    int b = (p>=248) ? 1 : 0;
    int i2 = p - b*248 + 8;
    int gb = 2*vbb + b;
    out[gb*256+i2]        = bf2f(toutl[g][b*256+i2]);
    out[2*BT+gb*256+i2]   = bf2f(extl[g][b*256+i2]);
  }
  #undef GSYNC
}

extern "C" void kernel_launch(void* const* d_in, const int* in_sizes, int n_in,
                              void* d_out, int out_size, void* d_ws, size_t ws_size,
                              hipStream_t stream)
{
  const float* in   = (const float*)d_in[0];
  const float* Wih  = (const float*)d_in[1];
  const float* Whh  = (const float*)d_in[2];
  const float* bih  = (const float*)d_in[3];
  const float* bhh  = (const float*)d_in[4];
  const float* fc1w = (const float*)d_in[5];
  const float* fc1b = (const float*)d_in[6];
  const float* fc2w = (const float*)d_in[7];
  const float* fc2b = (const float*)d_in[8];
  const float* i1w  = (const float*)d_in[9];
  const float* i1b  = (const float*)d_in[10];
  const float* i3w  = (const float*)d_in[11];
  const float* i3b  = (const float*)d_in[12];
  const float* scw  = (const float*)d_in[13];
  const float* zw   = (const float*)d_in[14];
  float* out = (float*)d_out;

  k_seq<<<dim3(128), dim3(512), 0, stream>>>(in, Wih, Whh, bih, bhh,
                                             fc1w, fc1b, fc2w, fc2b,
                                             i1w, i1b, i3w, i3b, scw, zw, out);
}